// Round 2
// baseline (348.893 us; speedup 1.0000x reference)
//
#include <hip/hip_runtime.h>
#include <hip/hip_bf16.h>
#include <math.h>

#define B_  16
#define N_  16
#define T_  48
#define C_  512
#define H_  8
#define HD_ 64
#define L_  768
#define BL_ 12288

typedef __attribute__((ext_vector_type(8))) short b16x8;
typedef __attribute__((ext_vector_type(4))) float f32x4;
typedef __attribute__((ext_vector_type(2))) unsigned int u32x2;

__device__ __forceinline__ short f2b(float f) {
  __hip_bfloat16 h = __float2bfloat16(f);
  return *reinterpret_cast<short*>(&h);
}
// fast RNE float->bf16 (no NaN handling; inputs finite)
__device__ __forceinline__ short brne(float f) {
  unsigned u = __float_as_uint(f);
  u += 0x7fffu + ((u >> 16) & 1u);
  return (short)(u >> 16);
}
// packed f32x2 -> bf16x2 (RNE), single VALU op
__device__ __forceinline__ unsigned cvt_pk_bf16(float a, float b) {
  unsigned d;
  asm("v_cvt_pk_bf16_f32 %0, %1, %2" : "=v"(d) : "v"(a), "v"(b));
  return d;
}

// ---------------------------------------------------------------------------
// prep: blocks [0,3072) cast x fp32->bf16; blocks [3072,4096) cast+transpose
// weights into WT[mat][n][k] (Wq pre-scaled by 1/8).
// ---------------------------------------------------------------------------
__global__ __launch_bounds__(256) void prep_kernel(
    const float* __restrict__ x,
    const float* __restrict__ Wq, const float* __restrict__ Wk,
    const float* __restrict__ Wv, const float* __restrict__ Wo,
    short* __restrict__ xb, short* __restrict__ WT)
{
  __shared__ float tile[32][33];
  int blk = blockIdx.x;
  int tid = threadIdx.x;
  if (blk < 3072) {
    int i = blk * 256 + tid;
    const float4* src = (const float4*)(x + (size_t)i * 8);
    float4 a = src[0], b = src[1];
    short tmp[8] = {f2b(a.x), f2b(a.y), f2b(a.z), f2b(a.w),
                    f2b(b.x), f2b(b.y), f2b(b.z), f2b(b.w)};
    *(b16x8*)(xb + (size_t)i * 8) = *(b16x8*)tmp;
  } else {
    int idx = blk - 3072;
    int mat = idx >> 8, rem = idx & 255;
    const float* W = (mat == 0) ? Wq : (mat == 1) ? Wk : (mat == 2) ? Wv : Wo;
    float scale = (mat == 0) ? 0.125f : 1.0f;
    int k0 = (rem >> 4) * 32, n0 = (rem & 15) * 32;
    int tx = tid & 31, ty = tid >> 5;
    for (int i = ty; i < 32; i += 8) tile[i][tx] = W[(size_t)(k0 + i) * 512 + n0 + tx];
    __syncthreads();
    short* dst = WT + (size_t)mat * 262144;
    for (int i = ty; i < 32; i += 8)
      dst[(size_t)(n0 + i) * 512 + k0 + tx] = f2b(tile[tx][i] * scale);
  }
}

// ---------------------------------------------------------------------------
// QKV GEMM, time-major permuted M-rows (rr = pt*16+pn) + LDS-staged epilogue.
//   q2,k2: [b][h][t][n][d]   vT2: [b][h][d][t][n]
// ---------------------------------------------------------------------------
__global__ __launch_bounds__(256) void qkv_kernel(
    const short* __restrict__ xb, const short* __restrict__ WT,
    short* __restrict__ q2, short* __restrict__ k2, short* __restrict__ vT2)
{
  __shared__ short smem[8192];              // As/Bs during K-loop; Ls in epilogue
  short (*As)[32] = (short(*)[32])smem;
  short (*Bs)[32] = (short(*)[32])(smem + 4096);
  int tid = threadIdx.x;
  int w = tid >> 6, lane = tid & 63, n16 = lane & 15, quad = lane >> 4;
  int bm = blockIdx.x, bn = blockIdx.y;
  int mat = bn >> 2;
  int ncol0 = (bn & 3) * 128;
  const short* Wt = WT + (size_t)mat * 262144;
  int bq = bm / 6;
  int rr0 = (bm % 6) * 128;

  f32x4 zero4 = {0.f, 0.f, 0.f, 0.f};
  f32x4 acc[4][4];
  #pragma unroll
  for (int mt = 0; mt < 4; ++mt)
    #pragma unroll
    for (int nt = 0; nt < 4; ++nt) acc[mt][nt] = zero4;

  int srow = tid >> 1, sch = (tid & 1) * 16;
  int rr = rr0 + srow;
  int pt = rr >> 4, pn = rr & 15;           // permuted row -> l = pn*48+pt
  const short* ga = xb + ((size_t)bq * 768 + pn * 48 + pt) * 512 + sch;
  const short* gb = Wt + (size_t)(ncol0 + srow) * 512 + sch;
  int wm = (w >> 1) * 64, wn = (w & 1) * 64;

  for (int kt = 0; kt < 16; ++kt) {
    b16x8 a0 = *(const b16x8*)(ga);
    b16x8 a1 = *(const b16x8*)(ga + 8);
    b16x8 b0 = *(const b16x8*)(gb);
    b16x8 b1 = *(const b16x8*)(gb + 8);
    ga += 32; gb += 32;
    __syncthreads();
    *(b16x8*)&As[srow][sch]     = a0;
    *(b16x8*)&As[srow][sch + 8] = a1;
    *(b16x8*)&Bs[srow][sch]     = b0;
    *(b16x8*)&Bs[srow][sch + 8] = b1;
    __syncthreads();
    b16x8 af[4], bf[4];
    #pragma unroll
    for (int mt = 0; mt < 4; ++mt) af[mt] = *(const b16x8*)&As[wm + mt * 16 + n16][quad * 8];
    #pragma unroll
    for (int nt = 0; nt < 4; ++nt) bf[nt] = *(const b16x8*)&Bs[wn + nt * 16 + n16][quad * 8];
    #pragma unroll
    for (int mt = 0; mt < 4; ++mt)
      #pragma unroll
      for (int nt = 0; nt < 4; ++nt)
        acc[mt][nt] = __builtin_amdgcn_mfma_f32_16x16x32_bf16(af[mt], bf[nt], acc[mt][nt], 0, 0, 0);
  }

  // epilogue: 4 chunks of 32 tile-rows staged through LDS, vector stores out
  short (*Ls)[136] = (short(*)[136])smem;   // 32 x 136 (pad: aligned, spread banks)
  for (int c = 0; c < 4; ++c) {
    __syncthreads();
    if ((w >> 1) == (c >> 1)) {             // waves owning rows 32c..32c+31
      int mtb = (c & 1) * 2;
      #pragma unroll
      for (int mi = 0; mi < 2; ++mi) {
        #pragma unroll
        for (int nt = 0; nt < 4; ++nt)
          #pragma unroll
          for (int r = 0; r < 4; ++r)
            Ls[mi * 16 + quad * 4 + r][wn + nt * 16 + n16] = f2b(acc[mtb + mi][nt][r]);
      }
    }
    __syncthreads();
    int rrc = rr0 + c * 32;
    if (mat != 2) {
      short* dst = (mat == 0) ? q2 : k2;
      int row = tid >> 3, c0 = (tid & 7) * 16;
      int hhg = (ncol0 + c0) >> 6, d0 = (ncol0 + c0) & 63;
      short* dp = dst + ((size_t)(bq * 8 + hhg) * 768 + rrc + row) * 64 + d0;
      *(b16x8*)dp       = *(b16x8*)&Ls[row][c0];
      *(b16x8*)(dp + 8) = *(b16x8*)&Ls[row][c0 + 8];
    } else {
      int cp = tid & 63, r8 = (tid >> 6) * 8;
      int c0 = 2 * cp;
      int hhg = (ncol0 + c0) >> 6, d0 = (ncol0 + c0) & 63;
      short t0[8], t1[8];
      #pragma unroll
      for (int j = 0; j < 8; ++j) { t0[j] = Ls[r8 + j][c0]; t1[j] = Ls[r8 + j][c0 + 1]; }
      short* dp = vT2 + ((size_t)(bq * 8 + hhg) * 64 + d0) * 768 + rrc + r8;
      *(b16x8*)dp         = *(b16x8*)t0;
      *(b16x8*)(dp + 768) = *(b16x8*)t1;
    }
  }
}

// ---------------------------------------------------------------------------
// Attention (R7 core): R6's swapped-QK^T in-register softmax, PLUS key-split —
// 4 waves/block (2 q-pairs x 2 key-parity halves). No-max softmax => partial
// (O, ps) over disjoint key subsets merge by pure addition through LDS.
// Doubles resident waves/CU (12 -> 24) and halves each wave's serial
// QK->exp->PV chain. Latency-bound kernel => ~2x expected.
// ---------------------------------------------------------------------------
__global__ __launch_bounds__(256, 6) void attn_kernel(
    const short* __restrict__ q2, const short* __restrict__ k2,
    const short* __restrict__ vT2,
    const float* __restrict__ relT, const float* __restrict__ relP,
    short* __restrict__ yatt)
{
  __shared__ float btL[2][96];
  __shared__ float mO[2][8][4][64];         // [pair][acc][r][lane] partial O
  __shared__ float mS[2][2][64];            // [pair][A/B][lane] partial ps

  int tid = threadIdx.x;
  int wv2 = tid >> 6, lane = tid & 63, n16 = lane & 15, quad = lane >> 4;
  int p  = wv2 & 1;                         // pair-in-block
  int kh = wv2 >> 1;                        // key-parity half (0=even kt2, 1=odd)
  int blk = blockIdx.x;
  int h = blk & 7;                          // XCD-locality
  int g = blk >> 3;
  int pg = g % 12, b = g / 12;
  int pair = pg * 2 + p;
  int qtA = pair, qtB = 47 - pair;
  int nA = (qtA + 2) >> 1, nB = (qtB + 2) >> 1;

  if (wv2 < 2) {
    btL[wv2][lane] = relT[(lane < 95 ? lane : 94) * 8 + h];
    if (lane < 32) btL[wv2][64 + lane] = relT[((64 + lane) < 95 ? 64 + lane : 94) * 8 + h];
  }
  __syncthreads();

  // swapped layout: reg r = key particle quad*4+r, lane n16 = q particle
  // bias_p[q][k] = relP[k - q + 15]
  float bpT[4];
  #pragma unroll
  for (int r = 0; r < 4; ++r)
    bpT[r] = relP[(quad * 4 + r - n16 + 15) * 8 + h];

  size_t bh = (size_t)(b * 8 + h);
  const short* qb = q2 + bh * 49152;
  const short* kb = k2 + bh * 49152;
  const short* vb = vT2 + bh * 49152;

  b16x8 qA0 = *(const b16x8*)(qb + (qtA * 16 + n16) * 64 + quad * 8);
  b16x8 qA1 = *(const b16x8*)(qb + (qtA * 16 + n16) * 64 + quad * 8 + 32);
  b16x8 qB0 = *(const b16x8*)(qb + (qtB * 16 + n16) * 64 + quad * 8);
  b16x8 qB1 = *(const b16x8*)(qb + (qtB * 16 + n16) * 64 + quad * 8 + 32);

  f32x4 zero4 = {0.f, 0.f, 0.f, 0.f};
  f32x4 oA[4], oB[4];
  float psA = 0.f, psB = 0.f;
  #pragma unroll
  for (int nt = 0; nt < 4; ++nt) { oA[nt] = zero4; oB[nt] = zero4; }

  b16x8 kfa[4], kfb[4], vfa[4], vfb[4];
  auto loadKV = [&](int kt2, b16x8* kf, b16x8* vf) {
    const short* kp = kb + (size_t)(kt2 * 32 + n16) * 64 + quad * 8;
    kf[0] = *(const b16x8*)kp;
    kf[1] = *(const b16x8*)(kp + 32);
    kf[2] = *(const b16x8*)(kp + 1024);
    kf[3] = *(const b16x8*)(kp + 1024 + 32);
    const short* vp = vb + (size_t)n16 * 768 + kt2 * 32 + quad * 8;
    vf[0] = *(const b16x8*)vp;
    vf[1] = *(const b16x8*)(vp + 16 * 768);
    vf[2] = *(const b16x8*)(vp + 32 * 768);
    vf[3] = *(const b16x8*)(vp + 48 * 768);
  };

  // exp+bias on S^T tile pair, pack to the PV A-fragment in-register.
  auto exp_pack = [&](const f32x4& s0, const f32x4& s1, float bt0, float bt1,
                      float& ps) -> b16x8 {
    float e00 = __expf(s0[0] + bt0 + bpT[0]);
    float e01 = __expf(s0[1] + bt0 + bpT[1]);
    float e02 = __expf(s0[2] + bt0 + bpT[2]);
    float e03 = __expf(s0[3] + bt0 + bpT[3]);
    float e10 = __expf(s1[0] + bt1 + bpT[0]);
    float e11 = __expf(s1[1] + bt1 + bpT[1]);
    float e12 = __expf(s1[2] + bt1 + bpT[2]);
    float e13 = __expf(s1[3] + bt1 + bpT[3]);
    ps += ((e00 + e01) + (e02 + e03)) + ((e10 + e11) + (e12 + e13));
    unsigned p0 = cvt_pk_bf16(e00, e01);
    unsigned p1 = cvt_pk_bf16(e02, e03);
    unsigned p2 = cvt_pk_bf16(e10, e11);
    unsigned p3 = cvt_pk_bf16(e12, e13);
    u32x2 a02 = __builtin_amdgcn_permlane32_swap(p0, p2, false, false);
    u32x2 z02 = __builtin_amdgcn_permlane16_swap(a02.x, a02.y, false, false);
    u32x2 a13 = __builtin_amdgcn_permlane32_swap(p1, p3, false, false);
    u32x2 z13 = __builtin_amdgcn_permlane16_swap(a13.x, a13.y, false, false);
    union { unsigned u[4]; b16x8 v; } r;
    r.u[0] = z02.x;
    r.u[1] = z13.x;
    r.u[2] = z02.y;
    r.u[3] = z13.y;
    return r.v;
  };

  auto step = [&](int kt2, const b16x8* kf, const b16x8* vf) {
    int kt0 = kt2 * 2;
    bool doA = kt2 < nA;                    // wave-uniform
    f32x4 sB0 = zero4, sB1 = zero4;
    sB0 = __builtin_amdgcn_mfma_f32_16x16x32_bf16(kf[0], qB0, sB0, 0, 0, 0);
    sB0 = __builtin_amdgcn_mfma_f32_16x16x32_bf16(kf[1], qB1, sB0, 0, 0, 0);
    sB1 = __builtin_amdgcn_mfma_f32_16x16x32_bf16(kf[2], qB0, sB1, 0, 0, 0);
    sB1 = __builtin_amdgcn_mfma_f32_16x16x32_bf16(kf[3], qB1, sB1, 0, 0, 0);
    f32x4 sA0 = zero4, sA1 = zero4;
    if (doA) {
      sA0 = __builtin_amdgcn_mfma_f32_16x16x32_bf16(kf[0], qA0, sA0, 0, 0, 0);
      sA0 = __builtin_amdgcn_mfma_f32_16x16x32_bf16(kf[1], qA1, sA0, 0, 0, 0);
      sA1 = __builtin_amdgcn_mfma_f32_16x16x32_bf16(kf[2], qA0, sA1, 0, 0, 0);
      sA1 = __builtin_amdgcn_mfma_f32_16x16x32_bf16(kf[3], qA1, sA1, 0, 0, 0);
    }
    float btB0 = (kt0 <= qtB) ? btL[p][kt0 - qtB + 47] : -1e30f;
    float btB1 = (kt0 + 1 <= qtB) ? btL[p][kt0 + 1 - qtB + 47] : -1e30f;
    b16x8 pfB = exp_pack(sB0, sB1, btB0, btB1, psB);
    #pragma unroll
    for (int nt = 0; nt < 4; ++nt)
      oB[nt] = __builtin_amdgcn_mfma_f32_16x16x32_bf16(pfB, vf[nt], oB[nt], 0, 0, 0);
    if (doA) {
      float btA0 = (kt0 <= qtA) ? btL[p][kt0 - qtA + 47] : -1e30f;
      float btA1 = (kt0 + 1 <= qtA) ? btL[p][kt0 + 1 - qtA + 47] : -1e30f;
      b16x8 pfA = exp_pack(sA0, sA1, btA0, btA1, psA);
      #pragma unroll
      for (int nt = 0; nt < 4; ++nt)
        oA[nt] = __builtin_amdgcn_mfma_f32_16x16x32_bf16(pfA, vf[nt], oA[nt], 0, 0, 0);
    }
  };

  // key-parity split: this wave handles kt2 = kh, kh+2, kh+4, ...
  loadKV(kh, kfa, vfa);
  for (int kt2 = kh; kt2 < nB; kt2 += 4) {
    if (kt2 + 2 < nB) loadKV(kt2 + 2, kfb, vfb);
    step(kt2, kfa, vfa);
    if (kt2 + 2 < nB) {
      if (kt2 + 4 < nB) loadKV(kt2 + 4, kfa, vfa);
      step(kt2 + 2, kfb, vfb);
    }
  }

  // merge the two key-halves through LDS (pure add: no-max softmax)
  if (kh == 1) {
    #pragma unroll
    for (int nt = 0; nt < 4; ++nt)
      #pragma unroll
      for (int r = 0; r < 4; ++r) {
        mO[p][nt][r][lane]     = oA[nt][r];
        mO[p][nt + 4][r][lane] = oB[nt][r];
      }
    mS[p][0][lane] = psA;
    mS[p][1][lane] = psB;
  }
  __syncthreads();
  if (kh == 1) return;
  #pragma unroll
  for (int nt = 0; nt < 4; ++nt)
    #pragma unroll
    for (int r = 0; r < 4; ++r) {
      oA[nt][r] += mO[p][nt][r][lane];
      oB[nt][r] += mO[p][nt + 4][r][lane];
    }
  psA += mS[p][0][lane];
  psB += mS[p][1][lane];

  // denom: per-lane partial (q = n16, keys split across quads) -> full sum
  psA += __shfl_xor(psA, 16); psA += __shfl_xor(psA, 32);
  psB += __shfl_xor(psB, 16); psB += __shfl_xor(psB, 32);
  float invA = 1.0f / psA, invB = 1.0f / psB;
  // redistribute to C-layout rows: lane needs 1/ps for q = quad*4+r
  float pnA[4], pnB[4];
  #pragma unroll
  for (int r = 0; r < 4; ++r) {
    pnA[r] = __shfl(invA, quad * 4 + r);
    pnB[r] = __shfl(invB, quad * 4 + r);
  }

  #pragma unroll
  for (int nt = 0; nt < 4; ++nt) {
    int c = h * 64 + nt * 16 + n16;
    #pragma unroll
    for (int r = 0; r < 4; ++r) {
      int qn = quad * 4 + r;
      yatt[((size_t)b * 768 + qn * 48 + qtA) * 512 + c] = f2b(oA[nt][r] * pnA[r]);
      yatt[((size_t)b * 768 + qn * 48 + qtB) * 512 + c] = f2b(oB[nt][r] * pnB[r]);
    }
  }
}

// ---------------------------------------------------------------------------
// proj: yatt(12288x512,bf16) @ WoT -> out fp32
// ---------------------------------------------------------------------------
__global__ __launch_bounds__(256) void proj_kernel(
    const short* __restrict__ yatt, const short* __restrict__ WT,
    float* __restrict__ out)
{
  __shared__ short As[128][32];
  __shared__ short Bs[128][32];
  int tid = threadIdx.x;
  int w = tid >> 6, lane = tid & 63, n16 = lane & 15, quad = lane >> 4;
  int row0 = blockIdx.x * 128;
  int ncol0 = blockIdx.y * 128;
  const short* Wt = WT + (size_t)3 * 262144;

  f32x4 zero4 = {0.f, 0.f, 0.f, 0.f};
  f32x4 acc[4][4];
  #pragma unroll
  for (int mt = 0; mt < 4; ++mt)
    #pragma unroll
    for (int nt = 0; nt < 4; ++nt) acc[mt][nt] = zero4;

  int srow = tid >> 1, sch = (tid & 1) * 16;
  const short* ga = yatt + (size_t)(row0 + srow) * 512 + sch;
  const short* gb = Wt + (size_t)(ncol0 + srow) * 512 + sch;
  int wm = (w >> 1) * 64, wn = (w & 1) * 64;

  for (int kt = 0; kt < 16; ++kt) {
    b16x8 a0 = *(const b16x8*)(ga);
    b16x8 a1 = *(const b16x8*)(ga + 8);
    b16x8 b0 = *(const b16x8*)(gb);
    b16x8 b1 = *(const b16x8*)(gb + 8);
    ga += 32; gb += 32;
    __syncthreads();
    *(b16x8*)&As[srow][sch]     = a0;
    *(b16x8*)&As[srow][sch + 8] = a1;
    *(b16x8*)&Bs[srow][sch]     = b0;
    *(b16x8*)&Bs[srow][sch + 8] = b1;
    __syncthreads();
    b16x8 af[4], bf[4];
    #pragma unroll
    for (int mt = 0; mt < 4; ++mt) af[mt] = *(const b16x8*)&As[wm + mt * 16 + n16][quad * 8];
    #pragma unroll
    for (int nt = 0; nt < 4; ++nt) bf[nt] = *(const b16x8*)&Bs[wn + nt * 16 + n16][quad * 8];
    #pragma unroll
    for (int mt = 0; mt < 4; ++mt)
      #pragma unroll
      for (int nt = 0; nt < 4; ++nt)
        acc[mt][nt] = __builtin_amdgcn_mfma_f32_16x16x32_bf16(af[mt], bf[nt], acc[mt][nt], 0, 0, 0);
  }

  #pragma unroll
  for (int mt = 0; mt < 4; ++mt) {
    int rowb = row0 + wm + mt * 16 + quad * 4;
    #pragma unroll
    for (int nt = 0; nt < 4; ++nt) {
      int colg = ncol0 + wn + nt * 16 + n16;
      #pragma unroll
      for (int r = 0; r < 4; ++r)
        out[(size_t)(rowb + r) * 512 + colg] = acc[mt][nt][r];
    }
  }
}

// ---------------------------------------------------------------------------
extern "C" void kernel_launch(void* const* d_in, const int* in_sizes, int n_in,
                              void* d_out, int out_size, void* d_ws, size_t ws_size,
                              hipStream_t stream) {
  const float* x    = (const float*)d_in[0];
  const float* Wq   = (const float*)d_in[1];
  const float* Wk   = (const float*)d_in[2];
  const float* Wv   = (const float*)d_in[3];
  const float* Wo   = (const float*)d_in[4];
  const float* relT = (const float*)d_in[5];
  const float* relP = (const float*)d_in[6];

  char* wsb = (char*)d_ws;
  const size_t SZ = (size_t)BL_ * C_ * 2;
  short* xb  = (short*)(wsb);
  short* WT  = (short*)(wsb + SZ);
  short* qb  = (short*)(wsb + SZ + 2097152);
  short* kb  = (short*)(wsb + 2 * SZ + 2097152);
  short* vTb = (short*)(wsb + 3 * SZ + 2097152);
  short* yat = (short*)(wsb + 4 * SZ + 2097152 + 4096);

  prep_kernel<<<dim3(4096), dim3(256), 0, stream>>>(x, Wq, Wk, Wv, Wo, xb, WT);
  qkv_kernel<<<dim3(96, 12), dim3(256), 0, stream>>>(xb, WT, qb, kb, vTb);
  attn_kernel<<<dim3(1536), dim3(256), 0, stream>>>(qb, kb, vTb, relT, relP, yat);
  proj_kernel<<<dim3(96, 4), dim3(256), 0, stream>>>(yat, WT, (float*)d_out);
}

// Round 3
// 222.239 us; speedup vs baseline: 1.5699x; 1.5699x over previous
//
#include <hip/hip_runtime.h>
#include <hip/hip_bf16.h>
#include <math.h>

#define B_  16
#define N_  16
#define T_  48
#define C_  512
#define H_  8
#define HD_ 64
#define L_  768
#define BL_ 12288

typedef __attribute__((ext_vector_type(8))) short b16x8;
typedef __attribute__((ext_vector_type(4))) float f32x4;
typedef __attribute__((ext_vector_type(2))) unsigned int u32x2;

__device__ __forceinline__ short f2b(float f) {
  __hip_bfloat16 h = __float2bfloat16(f);
  return *reinterpret_cast<short*>(&h);
}
// fast RNE float->bf16 (no NaN handling; inputs finite)
__device__ __forceinline__ short brne(float f) {
  unsigned u = __float_as_uint(f);
  u += 0x7fffu + ((u >> 16) & 1u);
  return (short)(u >> 16);
}
// packed f32x2 -> bf16x2 (RNE), single VALU op
__device__ __forceinline__ unsigned cvt_pk_bf16(float a, float b) {
  unsigned d;
  asm("v_cvt_pk_bf16_f32 %0, %1, %2" : "=v"(d) : "v"(a), "v"(b));
  return d;
}

// ---------------------------------------------------------------------------
// prep: blocks [0,3072) cast x fp32->bf16; blocks [3072,4096) cast+transpose
// weights into WT[mat][n][k] (Wq pre-scaled by 1/8).
// ---------------------------------------------------------------------------
__global__ __launch_bounds__(256) void prep_kernel(
    const float* __restrict__ x,
    const float* __restrict__ Wq, const float* __restrict__ Wk,
    const float* __restrict__ Wv, const float* __restrict__ Wo,
    short* __restrict__ xb, short* __restrict__ WT)
{
  __shared__ float tile[32][33];
  int blk = blockIdx.x;
  int tid = threadIdx.x;
  if (blk < 3072) {
    int i = blk * 256 + tid;
    const float4* src = (const float4*)(x + (size_t)i * 8);
    float4 a = src[0], b = src[1];
    short tmp[8] = {f2b(a.x), f2b(a.y), f2b(a.z), f2b(a.w),
                    f2b(b.x), f2b(b.y), f2b(b.z), f2b(b.w)};
    *(b16x8*)(xb + (size_t)i * 8) = *(b16x8*)tmp;
  } else {
    int idx = blk - 3072;
    int mat = idx >> 8, rem = idx & 255;
    const float* W = (mat == 0) ? Wq : (mat == 1) ? Wk : (mat == 2) ? Wv : Wo;
    float scale = (mat == 0) ? 0.125f : 1.0f;
    int k0 = (rem >> 4) * 32, n0 = (rem & 15) * 32;
    int tx = tid & 31, ty = tid >> 5;
    for (int i = ty; i < 32; i += 8) tile[i][tx] = W[(size_t)(k0 + i) * 512 + n0 + tx];
    __syncthreads();
    short* dst = WT + (size_t)mat * 262144;
    for (int i = ty; i < 32; i += 8)
      dst[(size_t)(n0 + i) * 512 + k0 + tx] = f2b(tile[tx][i] * scale);
  }
}

// ---------------------------------------------------------------------------
// QKV GEMM, time-major permuted M-rows (rr = pt*16+pn) + LDS-staged epilogue.
//   q2,k2: [b][h][t][n][d]   vT2: [b][h][d][t][n]
// ---------------------------------------------------------------------------
__global__ __launch_bounds__(256) void qkv_kernel(
    const short* __restrict__ xb, const short* __restrict__ WT,
    short* __restrict__ q2, short* __restrict__ k2, short* __restrict__ vT2)
{
  __shared__ short smem[8192];              // As/Bs during K-loop; Ls in epilogue
  short (*As)[32] = (short(*)[32])smem;
  short (*Bs)[32] = (short(*)[32])(smem + 4096);
  int tid = threadIdx.x;
  int w = tid >> 6, lane = tid & 63, n16 = lane & 15, quad = lane >> 4;
  int bm = blockIdx.x, bn = blockIdx.y;
  int mat = bn >> 2;
  int ncol0 = (bn & 3) * 128;
  const short* Wt = WT + (size_t)mat * 262144;
  int bq = bm / 6;
  int rr0 = (bm % 6) * 128;

  f32x4 zero4 = {0.f, 0.f, 0.f, 0.f};
  f32x4 acc[4][4];
  #pragma unroll
  for (int mt = 0; mt < 4; ++mt)
    #pragma unroll
    for (int nt = 0; nt < 4; ++nt) acc[mt][nt] = zero4;

  int srow = tid >> 1, sch = (tid & 1) * 16;
  int rr = rr0 + srow;
  int pt = rr >> 4, pn = rr & 15;           // permuted row -> l = pn*48+pt
  const short* ga = xb + ((size_t)bq * 768 + pn * 48 + pt) * 512 + sch;
  const short* gb = Wt + (size_t)(ncol0 + srow) * 512 + sch;
  int wm = (w >> 1) * 64, wn = (w & 1) * 64;

  for (int kt = 0; kt < 16; ++kt) {
    b16x8 a0 = *(const b16x8*)(ga);
    b16x8 a1 = *(const b16x8*)(ga + 8);
    b16x8 b0 = *(const b16x8*)(gb);
    b16x8 b1 = *(const b16x8*)(gb + 8);
    ga += 32; gb += 32;
    __syncthreads();
    *(b16x8*)&As[srow][sch]     = a0;
    *(b16x8*)&As[srow][sch + 8] = a1;
    *(b16x8*)&Bs[srow][sch]     = b0;
    *(b16x8*)&Bs[srow][sch + 8] = b1;
    __syncthreads();
    b16x8 af[4], bf[4];
    #pragma unroll
    for (int mt = 0; mt < 4; ++mt) af[mt] = *(const b16x8*)&As[wm + mt * 16 + n16][quad * 8];
    #pragma unroll
    for (int nt = 0; nt < 4; ++nt) bf[nt] = *(const b16x8*)&Bs[wn + nt * 16 + n16][quad * 8];
    #pragma unroll
    for (int mt = 0; mt < 4; ++mt)
      #pragma unroll
      for (int nt = 0; nt < 4; ++nt)
        acc[mt][nt] = __builtin_amdgcn_mfma_f32_16x16x32_bf16(af[mt], bf[nt], acc[mt][nt], 0, 0, 0);
  }

  // epilogue: 4 chunks of 32 tile-rows staged through LDS, vector stores out
  short (*Ls)[136] = (short(*)[136])smem;   // 32 x 136 (pad: aligned, spread banks)
  for (int c = 0; c < 4; ++c) {
    __syncthreads();
    if ((w >> 1) == (c >> 1)) {             // waves owning rows 32c..32c+31
      int mtb = (c & 1) * 2;
      #pragma unroll
      for (int mi = 0; mi < 2; ++mi) {
        #pragma unroll
        for (int nt = 0; nt < 4; ++nt)
          #pragma unroll
          for (int r = 0; r < 4; ++r)
            Ls[mi * 16 + quad * 4 + r][wn + nt * 16 + n16] = f2b(acc[mtb + mi][nt][r]);
      }
    }
    __syncthreads();
    int rrc = rr0 + c * 32;
    if (mat != 2) {
      short* dst = (mat == 0) ? q2 : k2;
      int row = tid >> 3, c0 = (tid & 7) * 16;
      int hhg = (ncol0 + c0) >> 6, d0 = (ncol0 + c0) & 63;
      short* dp = dst + ((size_t)(bq * 8 + hhg) * 768 + rrc + row) * 64 + d0;
      *(b16x8*)dp       = *(b16x8*)&Ls[row][c0];
      *(b16x8*)(dp + 8) = *(b16x8*)&Ls[row][c0 + 8];
    } else {
      int cp = tid & 63, r8 = (tid >> 6) * 8;
      int c0 = 2 * cp;
      int hhg = (ncol0 + c0) >> 6, d0 = (ncol0 + c0) & 63;
      short t0[8], t1[8];
      #pragma unroll
      for (int j = 0; j < 8; ++j) { t0[j] = Ls[r8 + j][c0]; t1[j] = Ls[r8 + j][c0 + 1]; }
      short* dp = vT2 + ((size_t)(bq * 8 + hhg) * 64 + d0) * 768 + rrc + r8;
      *(b16x8*)dp         = *(b16x8*)t0;
      *(b16x8*)(dp + 768) = *(b16x8*)t1;
    }
  }
}

// ---------------------------------------------------------------------------
// Attention (R8 core): one q-band per WAVE (R6 packed two bands per wave).
// Grid 3072 x 2 waves = 6144 waves (24/CU vs R6's 12). Per-wave regs ~77
// (q 8 + K 16 + V 16 + acc 16 + misc) -> 6 waves/SIMD fit WITHOUT spill
// (R7's launch_bounds(256,6) capped unified regs at 85 vs 112 needed ->
// 520 MB scratch traffic; this cuts state instead of forcing the cap).
// No K/V double-buffer: TLP replaces ILP. No __syncthreads in body.
// ---------------------------------------------------------------------------
__global__ __launch_bounds__(128, 5) void attn_kernel(
    const short* __restrict__ q2, const short* __restrict__ k2,
    const short* __restrict__ vT2,
    const float* __restrict__ relT, const float* __restrict__ relP,
    short* __restrict__ yatt)
{
  __shared__ float btL[2][96];              // per-wave copy; no barrier needed

  int tid = threadIdx.x;
  int wv = tid >> 6, lane = tid & 63, n16 = lane & 15, quad = lane >> 4;
  int blk = blockIdx.x;
  int h = blk & 7;                          // XCD-locality: (b,h) pinned to XCD
  int g = blk >> 3;                         // 0..383
  int pg = g % 24, b = g / 24;
  int qt = wv ? (47 - pg) : pg;             // block-balanced causal pair
  int nQ = (qt + 2) >> 1;                   // # of 32-key steps

  btL[wv][lane] = relT[(lane < 95 ? lane : 94) * 8 + h];
  if (lane < 32) btL[wv][64 + lane] = relT[((64 + lane) < 95 ? 64 + lane : 94) * 8 + h];

  // swapped layout: reg r = key particle quad*4+r, lane n16 = q particle
  // bias_p[q][k] = relP[k - q + 15]
  float bpT[4];
  #pragma unroll
  for (int r = 0; r < 4; ++r)
    bpT[r] = relP[(quad * 4 + r - n16 + 15) * 8 + h];

  size_t bh = (size_t)(b * 8 + h);
  const short* qb = q2 + bh * 49152;
  const short* kb = k2 + bh * 49152;
  const short* vb = vT2 + bh * 49152;

  b16x8 q0 = *(const b16x8*)(qb + (qt * 16 + n16) * 64 + quad * 8);
  b16x8 q1 = *(const b16x8*)(qb + (qt * 16 + n16) * 64 + quad * 8 + 32);

  f32x4 zero4 = {0.f, 0.f, 0.f, 0.f};
  f32x4 o[4];
  float ps = 0.f;
  #pragma unroll
  for (int nt = 0; nt < 4; ++nt) o[nt] = zero4;

  for (int kt2 = 0; kt2 < nQ; ++kt2) {
    // K fragment loads (keys kt2*32 .. +31, two 16-key groups)
    const short* kp = kb + (size_t)(kt2 * 32 + n16) * 64 + quad * 8;
    b16x8 k0 = *(const b16x8*)kp;
    b16x8 k1 = *(const b16x8*)(kp + 32);
    b16x8 k2f = *(const b16x8*)(kp + 1024);
    b16x8 k3 = *(const b16x8*)(kp + 1024 + 32);
    // V fragment loads issued now (independent of QK) -> latency hides
    // under QK-MFMA + exp while this wave, and under other waves via TLP
    const short* vp = vb + (size_t)n16 * 768 + kt2 * 32 + quad * 8;
    b16x8 v0 = *(const b16x8*)vp;
    b16x8 v1 = *(const b16x8*)(vp + 16 * 768);
    b16x8 v2 = *(const b16x8*)(vp + 32 * 768);
    b16x8 v3 = *(const b16x8*)(vp + 48 * 768);

    // swapped QK^T: S^T[key][q] — lane&15 = q, rows = key particle
    f32x4 s0 = zero4, s1 = zero4;
    s0 = __builtin_amdgcn_mfma_f32_16x16x32_bf16(k0, q0, s0, 0, 0, 0);
    s0 = __builtin_amdgcn_mfma_f32_16x16x32_bf16(k1, q1, s0, 0, 0, 0);
    s1 = __builtin_amdgcn_mfma_f32_16x16x32_bf16(k2f, q0, s1, 0, 0, 0);
    s1 = __builtin_amdgcn_mfma_f32_16x16x32_bf16(k3, q1, s1, 0, 0, 0);

    int kt0 = kt2 * 2;
    float bt0 = (kt0 <= qt) ? btL[wv][kt0 - qt + 47] : -1e30f;      // uniform
    float bt1 = (kt0 + 1 <= qt) ? btL[wv][kt0 + 1 - qt + 47] : -1e30f;

    // exp+bias, pack to PV A-fragment in-register (cvt_pk + permlane swaps)
    float e00 = __expf(s0[0] + bt0 + bpT[0]);
    float e01 = __expf(s0[1] + bt0 + bpT[1]);
    float e02 = __expf(s0[2] + bt0 + bpT[2]);
    float e03 = __expf(s0[3] + bt0 + bpT[3]);
    float e10 = __expf(s1[0] + bt1 + bpT[0]);
    float e11 = __expf(s1[1] + bt1 + bpT[1]);
    float e12 = __expf(s1[2] + bt1 + bpT[2]);
    float e13 = __expf(s1[3] + bt1 + bpT[3]);
    ps += ((e00 + e01) + (e02 + e03)) + ((e10 + e11) + (e12 + e13));
    unsigned p0 = cvt_pk_bf16(e00, e01);    // particles 4q+0,1  @ t0
    unsigned p1 = cvt_pk_bf16(e02, e03);    // particles 4q+2,3  @ t0
    unsigned p2 = cvt_pk_bf16(e10, e11);    // particles 4q+0,1  @ t1
    unsigned p3 = cvt_pk_bf16(e12, e13);    // particles 4q+2,3  @ t1
    u32x2 a02 = __builtin_amdgcn_permlane32_swap(p0, p2, false, false);
    u32x2 z02 = __builtin_amdgcn_permlane16_swap(a02.x, a02.y, false, false);
    u32x2 a13 = __builtin_amdgcn_permlane32_swap(p1, p3, false, false);
    u32x2 z13 = __builtin_amdgcn_permlane16_swap(a13.x, a13.y, false, false);
    union { unsigned u[4]; b16x8 v; } pf;
    pf.u[0] = z02.x;                        // keys 8qt+0,1
    pf.u[1] = z13.x;                        // keys 8qt+2,3
    pf.u[2] = z02.y;                        // keys 8qt+4,5
    pf.u[3] = z13.y;                        // keys 8qt+6,7

    o[0] = __builtin_amdgcn_mfma_f32_16x16x32_bf16(pf.v, v0, o[0], 0, 0, 0);
    o[1] = __builtin_amdgcn_mfma_f32_16x16x32_bf16(pf.v, v1, o[1], 0, 0, 0);
    o[2] = __builtin_amdgcn_mfma_f32_16x16x32_bf16(pf.v, v2, o[2], 0, 0, 0);
    o[3] = __builtin_amdgcn_mfma_f32_16x16x32_bf16(pf.v, v3, o[3], 0, 0, 0);
  }

  // denom: per-lane partial (q = n16, keys split across quads) -> full sum
  ps += __shfl_xor(ps, 16);
  ps += __shfl_xor(ps, 32);
  float inv = 1.0f / ps;
  // redistribute to C-layout rows: lane needs 1/ps for q = quad*4+r
  float pn[4];
  #pragma unroll
  for (int r = 0; r < 4; ++r) pn[r] = __shfl(inv, quad * 4 + r);

  #pragma unroll
  for (int nt = 0; nt < 4; ++nt) {
    int c = h * 64 + nt * 16 + n16;
    #pragma unroll
    for (int r = 0; r < 4; ++r) {
      int qn = quad * 4 + r;
      yatt[((size_t)b * 768 + qn * 48 + qt) * 512 + c] = f2b(o[nt][r] * pn[r]);
    }
  }
}

// ---------------------------------------------------------------------------
// proj: yatt(12288x512,bf16) @ WoT -> out fp32
// ---------------------------------------------------------------------------
__global__ __launch_bounds__(256) void proj_kernel(
    const short* __restrict__ yatt, const short* __restrict__ WT,
    float* __restrict__ out)
{
  __shared__ short As[128][32];
  __shared__ short Bs[128][32];
  int tid = threadIdx.x;
  int w = tid >> 6, lane = tid & 63, n16 = lane & 15, quad = lane >> 4;
  int row0 = blockIdx.x * 128;
  int ncol0 = blockIdx.y * 128;
  const short* Wt = WT + (size_t)3 * 262144;

  f32x4 zero4 = {0.f, 0.f, 0.f, 0.f};
  f32x4 acc[4][4];
  #pragma unroll
  for (int mt = 0; mt < 4; ++mt)
    #pragma unroll
    for (int nt = 0; nt < 4; ++nt) acc[mt][nt] = zero4;

  int srow = tid >> 1, sch = (tid & 1) * 16;
  const short* ga = yatt + (size_t)(row0 + srow) * 512 + sch;
  const short* gb = Wt + (size_t)(ncol0 + srow) * 512 + sch;
  int wm = (w >> 1) * 64, wn = (w & 1) * 64;

  for (int kt = 0; kt < 16; ++kt) {
    b16x8 a0 = *(const b16x8*)(ga);
    b16x8 a1 = *(const b16x8*)(ga + 8);
    b16x8 b0 = *(const b16x8*)(gb);
    b16x8 b1 = *(const b16x8*)(gb + 8);
    ga += 32; gb += 32;
    __syncthreads();
    *(b16x8*)&As[srow][sch]     = a0;
    *(b16x8*)&As[srow][sch + 8] = a1;
    *(b16x8*)&Bs[srow][sch]     = b0;
    *(b16x8*)&Bs[srow][sch + 8] = b1;
    __syncthreads();
    b16x8 af[4], bf[4];
    #pragma unroll
    for (int mt = 0; mt < 4; ++mt) af[mt] = *(const b16x8*)&As[wm + mt * 16 + n16][quad * 8];
    #pragma unroll
    for (int nt = 0; nt < 4; ++nt) bf[nt] = *(const b16x8*)&Bs[wn + nt * 16 + n16][quad * 8];
    #pragma unroll
    for (int mt = 0; mt < 4; ++mt)
      #pragma unroll
      for (int nt = 0; nt < 4; ++nt)
        acc[mt][nt] = __builtin_amdgcn_mfma_f32_16x16x32_bf16(af[mt], bf[nt], acc[mt][nt], 0, 0, 0);
  }

  #pragma unroll
  for (int mt = 0; mt < 4; ++mt) {
    int rowb = row0 + wm + mt * 16 + quad * 4;
    #pragma unroll
    for (int nt = 0; nt < 4; ++nt) {
      int colg = ncol0 + wn + nt * 16 + n16;
      #pragma unroll
      for (int r = 0; r < 4; ++r)
        out[(size_t)(rowb + r) * 512 + colg] = acc[mt][nt][r];
    }
  }
}

// ---------------------------------------------------------------------------
extern "C" void kernel_launch(void* const* d_in, const int* in_sizes, int n_in,
                              void* d_out, int out_size, void* d_ws, size_t ws_size,
                              hipStream_t stream) {
  const float* x    = (const float*)d_in[0];
  const float* Wq   = (const float*)d_in[1];
  const float* Wk   = (const float*)d_in[2];
  const float* Wv   = (const float*)d_in[3];
  const float* Wo   = (const float*)d_in[4];
  const float* relT = (const float*)d_in[5];
  const float* relP = (const float*)d_in[6];

  char* wsb = (char*)d_ws;
  const size_t SZ = (size_t)BL_ * C_ * 2;
  short* xb  = (short*)(wsb);
  short* WT  = (short*)(wsb + SZ);
  short* qb  = (short*)(wsb + SZ + 2097152);
  short* kb  = (short*)(wsb + 2 * SZ + 2097152);
  short* vTb = (short*)(wsb + 3 * SZ + 2097152);
  short* yat = (short*)(wsb + 4 * SZ + 2097152 + 4096);

  prep_kernel<<<dim3(4096), dim3(256), 0, stream>>>(x, Wq, Wk, Wv, Wo, xb, WT);
  qkv_kernel<<<dim3(96, 12), dim3(256), 0, stream>>>(xb, WT, qb, kb, vTb);
  attn_kernel<<<dim3(3072), dim3(128), 0, stream>>>(qb, kb, vTb, relT, relP, yat);
  proj_kernel<<<dim3(96, 4), dim3(256), 0, stream>>>(yat, WT, (float*)d_out);
}